// Round 1
// baseline (1777.480 us; speedup 1.0000x reference)
//
#include <hip/hip_runtime.h>
#include <hip/hip_bf16.h>
#include <stdint.h>

#define TOKENS 8192
#define OUTF   11008
#define INF    4096
#define NCODES (45088768)   // OUTF * INF

typedef __bf16 bf16x8 __attribute__((ext_vector_type(8)));
typedef float  f32x4  __attribute__((ext_vector_type(4)));

__device__ __forceinline__ unsigned short f32_to_bf16_rne(float f) {
    union { float f; unsigned int u; } v; v.f = f;
    unsigned int u = v.u;
    unsigned int r = u + 0x7fffu + ((u >> 16) & 1u);
    return (unsigned short)(r >> 16);
}

// ---------------- dequant W: codes(int32) * codebook * absmax -> bf16 ----------------
__global__ __launch_bounds__(256) void dequant_w(const int* __restrict__ codes,
                                                 const float* __restrict__ absmax,
                                                 const float* __restrict__ codebook,
                                                 unsigned short* __restrict__ wq) {
    __shared__ float cb[16];
    if (threadIdx.x < 16) cb[threadIdx.x] = codebook[threadIdx.x];
    __syncthreads();
    size_t idx = ((size_t)blockIdx.x * 256 + threadIdx.x) * 8;   // grid sized exactly
    float am = absmax[idx >> 6];                                  // 8 | 64 -> one block per thread-chunk
    const int4* cp = (const int4*)(codes + idx);
    int4 c0 = cp[0];
    int4 c1 = cp[1];
    union { unsigned short s[8]; uint4 v; } u;
    u.s[0] = f32_to_bf16_rne(cb[c0.x] * am);
    u.s[1] = f32_to_bf16_rne(cb[c0.y] * am);
    u.s[2] = f32_to_bf16_rne(cb[c0.z] * am);
    u.s[3] = f32_to_bf16_rne(cb[c0.w] * am);
    u.s[4] = f32_to_bf16_rne(cb[c1.x] * am);
    u.s[5] = f32_to_bf16_rne(cb[c1.y] * am);
    u.s[6] = f32_to_bf16_rne(cb[c1.z] * am);
    u.s[7] = f32_to_bf16_rne(cb[c1.w] * am);
    *(uint4*)(wq + idx) = u.v;
}

// ---------------- cast x: fp32 -> bf16 ----------------
__global__ __launch_bounds__(256) void cast_x(const float* __restrict__ x,
                                              unsigned short* __restrict__ xq) {
    size_t idx = ((size_t)blockIdx.x * 256 + threadIdx.x) * 8;   // grid sized exactly
    float4 a = *(const float4*)(x + idx);
    float4 b = *(const float4*)(x + idx + 4);
    union { unsigned short s[8]; uint4 v; } u;
    u.s[0] = f32_to_bf16_rne(a.x);
    u.s[1] = f32_to_bf16_rne(a.y);
    u.s[2] = f32_to_bf16_rne(a.z);
    u.s[3] = f32_to_bf16_rne(a.w);
    u.s[4] = f32_to_bf16_rne(b.x);
    u.s[5] = f32_to_bf16_rne(b.y);
    u.s[6] = f32_to_bf16_rne(b.z);
    u.s[7] = f32_to_bf16_rne(b.w);
    *(uint4*)(xq + idx) = u.v;
}

// ---------------- bf16 MFMA GEMM: C[M,N] = X[M,K] * W[N,K]^T + bias ----------------
// m97-recipe: 128x128 tile, BK=32, 256 threads (4 waves, 2x2 quadrants of 64x64),
// global_load_lds width=16 staging, ds_read_b128 fragment loads, 16x16x32 bf16 MFMA.
#define BM 128
#define BN 128
#define BK 32

__global__ __launch_bounds__(256) void gemm_bf16(const unsigned short* __restrict__ Xb,  // [TOKENS][INF]
                                                 const unsigned short* __restrict__ Wb,  // [OUTF][INF]
                                                 const float* __restrict__ bias,
                                                 float* __restrict__ out) {
    __shared__ __align__(16) unsigned short lA[BM * BK];  // [128][32], row-major, no pad (global_load_lds)
    __shared__ __align__(16) unsigned short lB[BN * BK];

    const int tid  = threadIdx.x;
    const int lane = tid & 63;
    const int wave = tid >> 6;
    const int wm = (wave >> 1) * 64;   // wave quadrant row
    const int wn = (wave & 1) * 64;    // wave quadrant col
    const int m0 = blockIdx.y * BM;
    const int n0 = blockIdx.x * BN;

    f32x4 acc[4][4];
#pragma unroll
    for (int i = 0; i < 4; i++)
#pragma unroll
        for (int j = 0; j < 4; j++)
#pragma unroll
            for (int r = 0; r < 4; r++) acc[i][j][r] = 0.0f;

    // staging: tile = 128 rows x 32 bf16 = 512 chunks of 16B; thread does chunks tid, tid+256
    const int ch0 = tid, ch1 = tid + 256;
    const int rA0 = ch0 >> 2, kA0 = (ch0 & 3) * 8;
    const int rA1 = ch1 >> 2, kA1 = (ch1 & 3) * 8;
    const unsigned short* gA0 = Xb + (size_t)(m0 + rA0) * INF + kA0;
    const unsigned short* gA1 = Xb + (size_t)(m0 + rA1) * INF + kA1;
    const unsigned short* gB0 = Wb + (size_t)(n0 + rA0) * INF + kA0;
    const unsigned short* gB1 = Wb + (size_t)(n0 + rA1) * INF + kA1;
    unsigned short* lA0 = &lA[ch0 * 8];
    unsigned short* lA1 = &lA[ch1 * 8];
    unsigned short* lB0 = &lB[ch0 * 8];
    unsigned short* lB1 = &lB[ch1 * 8];

    const int frow = lane & 15;          // fragment row within 16x16 tile
    const int kgrp = (lane >> 4) * 8;    // k-group base (8 contiguous bf16)

    for (int k0 = 0; k0 < INF; k0 += BK) {
        __syncthreads();  // previous iter's LDS reads done before overwrite
        __builtin_amdgcn_global_load_lds((const __attribute__((address_space(1))) void*)(gA0 + k0),
                                         (__attribute__((address_space(3))) void*)lA0, 16, 0, 0);
        __builtin_amdgcn_global_load_lds((const __attribute__((address_space(1))) void*)(gA1 + k0),
                                         (__attribute__((address_space(3))) void*)lA1, 16, 0, 0);
        __builtin_amdgcn_global_load_lds((const __attribute__((address_space(1))) void*)(gB0 + k0),
                                         (__attribute__((address_space(3))) void*)lB0, 16, 0, 0);
        __builtin_amdgcn_global_load_lds((const __attribute__((address_space(1))) void*)(gB1 + k0),
                                         (__attribute__((address_space(3))) void*)lB1, 16, 0, 0);
        __syncthreads();  // compiler drains vmcnt(0) before s_barrier -> LDS data visible

        bf16x8 af[4], bfr[4];
#pragma unroll
        for (int i = 0; i < 4; i++)
            af[i] = *(const bf16x8*)&lA[(wm + i * 16 + frow) * BK + kgrp];
#pragma unroll
        for (int j = 0; j < 4; j++)
            bfr[j] = *(const bf16x8*)&lB[(wn + j * 16 + frow) * BK + kgrp];
#pragma unroll
        for (int i = 0; i < 4; i++)
#pragma unroll
            for (int j = 0; j < 4; j++)
                acc[i][j] = __builtin_amdgcn_mfma_f32_16x16x32_bf16(af[i], bfr[j], acc[i][j], 0, 0, 0);
    }

    // epilogue: C/D layout col=lane&15, row=(lane>>4)*4+reg  [m89/m91-verified]
    const int crow = (lane >> 4) * 4;
    const int ccol = lane & 15;
#pragma unroll
    for (int j = 0; j < 4; j++) {
        const int n = n0 + wn + j * 16 + ccol;
        const float bv = bias[n];
#pragma unroll
        for (int i = 0; i < 4; i++) {
            const int m = m0 + wm + i * 16 + crow;
#pragma unroll
            for (int r = 0; r < 4; r++)
                out[(size_t)(m + r) * OUTF + n] = acc[i][j][r] + bv;
        }
    }
}

// ---------------- fallback (ws too small): fused fp32 tiled GEMM ----------------
__global__ __launch_bounds__(256) void fused_fallback(const float* __restrict__ x,
                                                      const int* __restrict__ codes,
                                                      const float* __restrict__ absmax,
                                                      const float* __restrict__ codebook,
                                                      const float* __restrict__ bias,
                                                      float* __restrict__ out) {
    __shared__ float xs[64][17];
    __shared__ float wsm[64][17];
    __shared__ float cb[16];
    const int tid = threadIdx.x;
    if (tid < 16) cb[tid] = codebook[tid];
    const int m0 = blockIdx.y * 64, n0 = blockIdx.x * 64;
    float acc[4][4] = {};
    const int tr = tid >> 4, tc = tid & 15;
    for (int k0 = 0; k0 < INF; k0 += 16) {
        __syncthreads();
#pragma unroll
        for (int i = 0; i < 4; i++) {
            int e = i * 256 + tid;
            int r = e >> 4, c = e & 15;
            xs[r][c] = x[(size_t)(m0 + r) * INF + k0 + c];
            size_t widx = (size_t)(n0 + r) * INF + k0 + c;
            wsm[r][c] = cb[codes[widx]] * absmax[widx >> 6];
        }
        __syncthreads();
#pragma unroll
        for (int kk = 0; kk < 16; kk++) {
            float xv[4], wv[4];
#pragma unroll
            for (int i = 0; i < 4; i++) xv[i] = xs[tr * 4 + i][kk];
#pragma unroll
            for (int j = 0; j < 4; j++) wv[j] = wsm[tc * 4 + j][kk];
#pragma unroll
            for (int i = 0; i < 4; i++)
#pragma unroll
                for (int j = 0; j < 4; j++) acc[i][j] += xv[i] * wv[j];
        }
    }
#pragma unroll
    for (int i = 0; i < 4; i++)
#pragma unroll
        for (int j = 0; j < 4; j++) {
            int m = m0 + tr * 4 + i, n = n0 + tc * 4 + j;
            out[(size_t)m * OUTF + n] = acc[i][j] + bias[n];
        }
}

extern "C" void kernel_launch(void* const* d_in, const int* in_sizes, int n_in,
                              void* d_out, int out_size, void* d_ws, size_t ws_size,
                              hipStream_t stream) {
    const float* x        = (const float*)d_in[0];
    const int*   codes    = (const int*)d_in[1];
    const float* absmax   = (const float*)d_in[2];
    const float* codebook = (const float*)d_in[3];
    const float* bias     = (const float*)d_in[4];
    float* out = (float*)d_out;

    const size_t wbytes = (size_t)NCODES * 2;                 // 90.2 MB bf16 W
    const size_t xbytes = (size_t)TOKENS * INF * 2;           // 67.1 MB bf16 X

    if (ws_size >= wbytes + xbytes) {
        unsigned short* wq = (unsigned short*)d_ws;
        unsigned short* xq = (unsigned short*)((char*)d_ws + wbytes);
        dequant_w<<<NCODES / 2048, 256, 0, stream>>>(codes, absmax, codebook, wq);
        cast_x<<<(TOKENS * INF) / 2048, 256, 0, stream>>>(x, xq);
        dim3 grid(OUTF / BN, TOKENS / BM);   // 86 x 64
        gemm_bf16<<<grid, 256, 0, stream>>>(xq, wq, bias, out);
    } else {
        dim3 grid(OUTF / 64, TOKENS / 64);
        fused_fallback<<<grid, 256, 0, stream>>>(x, codes, absmax, codebook, bias, out);
    }
}

// Round 2
// 1437.425 us; speedup vs baseline: 1.2366x; 1.2366x over previous
//
#include <hip/hip_runtime.h>
#include <hip/hip_bf16.h>
#include <stdint.h>

#define TOKENS 8192
#define OUTF   11008
#define INF    4096
#define NCODES (45088768)   // OUTF * INF

typedef __bf16 bf16x8 __attribute__((ext_vector_type(8)));
typedef float  f32x4  __attribute__((ext_vector_type(4)));

__device__ __forceinline__ unsigned short f32_to_bf16_rne(float f) {
    union { float f; unsigned int u; } v; v.f = f;
    unsigned int u = v.u;
    unsigned int r = u + 0x7fffu + ((u >> 16) & 1u);
    return (unsigned short)(r >> 16);
}

// ---------------- dequant W: codes(int32) * codebook * absmax -> bf16 ----------------
__global__ __launch_bounds__(256) void dequant_w(const int* __restrict__ codes,
                                                 const float* __restrict__ absmax,
                                                 const float* __restrict__ codebook,
                                                 unsigned short* __restrict__ wq) {
    __shared__ float cb[16];
    if (threadIdx.x < 16) cb[threadIdx.x] = codebook[threadIdx.x];
    __syncthreads();
    size_t idx = ((size_t)blockIdx.x * 256 + threadIdx.x) * 8;   // grid sized exactly
    float am = absmax[idx >> 6];                                  // 8 | 64 -> one absmax per 8-chunk
    const int4* cp = (const int4*)(codes + idx);
    int4 c0 = cp[0];
    int4 c1 = cp[1];
    union { unsigned short s[8]; uint4 v; } u;
    u.s[0] = f32_to_bf16_rne(cb[c0.x] * am);
    u.s[1] = f32_to_bf16_rne(cb[c0.y] * am);
    u.s[2] = f32_to_bf16_rne(cb[c0.z] * am);
    u.s[3] = f32_to_bf16_rne(cb[c0.w] * am);
    u.s[4] = f32_to_bf16_rne(cb[c1.x] * am);
    u.s[5] = f32_to_bf16_rne(cb[c1.y] * am);
    u.s[6] = f32_to_bf16_rne(cb[c1.z] * am);
    u.s[7] = f32_to_bf16_rne(cb[c1.w] * am);
    *(uint4*)(wq + idx) = u.v;
}

// ---------------- cast x: fp32 -> bf16 ----------------
__global__ __launch_bounds__(256) void cast_x(const float* __restrict__ x,
                                              unsigned short* __restrict__ xq) {
    size_t idx = ((size_t)blockIdx.x * 256 + threadIdx.x) * 8;   // grid sized exactly
    float4 a = *(const float4*)(x + idx);
    float4 b = *(const float4*)(x + idx + 4);
    union { unsigned short s[8]; uint4 v; } u;
    u.s[0] = f32_to_bf16_rne(a.x);
    u.s[1] = f32_to_bf16_rne(a.y);
    u.s[2] = f32_to_bf16_rne(a.z);
    u.s[3] = f32_to_bf16_rne(a.w);
    u.s[4] = f32_to_bf16_rne(b.x);
    u.s[5] = f32_to_bf16_rne(b.y);
    u.s[6] = f32_to_bf16_rne(b.z);
    u.s[7] = f32_to_bf16_rne(b.w);
    *(uint4*)(xq + idx) = u.v;
}

// ---------------- bf16 MFMA GEMM: C[M,N] = X[M,K] * W[N,K]^T + bias ----------------
// m97-recipe: 128x128 tile, BK=32, 256 threads (4 waves, 2x2 quadrants of 64x64),
// global_load_lds width=16 staging, ds_read_b128 fragment loads, 16x16x32 bf16 MFMA.
// R1: XCD-aware swizzle. bid%8 = XCD (round-robin dispatch heuristic); each XCD owns
// a 16m x 43n region of the 64x86 tile grid, iterated in 8-wide n-sub-columns
// (16x8 = 128 blocks ~= per-XCD concurrent window at 3 blocks/CU x 32 CUs).
// Concurrent same-XCD blocks then share 16 X-stripes + 8 W-stripes; their per-BK
// k-slices (~200 KB) fit the 4 MB per-XCD L2 -> FETCH should drop ~3x.
#define BM 128
#define BN 128
#define BK 32

__global__ __launch_bounds__(256) void gemm_bf16(const unsigned short* __restrict__ Xb,  // [TOKENS][INF]
                                                 const unsigned short* __restrict__ Wb,  // [OUTF][INF]
                                                 const float* __restrict__ bias,
                                                 float* __restrict__ out) {
    __shared__ __align__(16) unsigned short lA[BM * BK];  // [128][32], row-major, no pad (global_load_lds)
    __shared__ __align__(16) unsigned short lB[BN * BK];

    // ---- XCD-aware swizzle: 64 m-tiles x 86 n-tiles, 5504 blocks, 1D grid ----
    const int bid  = blockIdx.x;
    const int xcd  = bid & 7;          // round-robin workgroup->XCD heuristic
    const int slot = bid >> 3;         // 0..687 within this XCD's region
    const int mpart = xcd >> 1;        // 4 m-parts of 16 tiles
    const int npart = xcd & 1;         // 2 n-parts of 43 tiles
    const int sub  = slot >> 7;        // sub-column of 8 n-tiles (128 blocks); sub 5 has 3 n-tiles
    const int rem  = slot & 127;
    const int mloc = rem & 15;
    const int nloc = sub * 8 + (rem >> 4);
    const int m0 = (mpart * 16 + mloc) * BM;
    const int n0 = (npart * 43 + nloc) * BN;

    const int tid  = threadIdx.x;
    const int lane = tid & 63;
    const int wave = tid >> 6;
    const int wm = (wave >> 1) * 64;   // wave quadrant row
    const int wn = (wave & 1) * 64;    // wave quadrant col

    f32x4 acc[4][4];
#pragma unroll
    for (int i = 0; i < 4; i++)
#pragma unroll
        for (int j = 0; j < 4; j++)
#pragma unroll
            for (int r = 0; r < 4; r++) acc[i][j][r] = 0.0f;

    // staging: tile = 128 rows x 32 bf16 = 512 chunks of 16B; thread does chunks tid, tid+256
    const int ch0 = tid, ch1 = tid + 256;
    const int rA0 = ch0 >> 2, kA0 = (ch0 & 3) * 8;
    const int rA1 = ch1 >> 2, kA1 = (ch1 & 3) * 8;
    const unsigned short* gA0 = Xb + (size_t)(m0 + rA0) * INF + kA0;
    const unsigned short* gA1 = Xb + (size_t)(m0 + rA1) * INF + kA1;
    const unsigned short* gB0 = Wb + (size_t)(n0 + rA0) * INF + kA0;
    const unsigned short* gB1 = Wb + (size_t)(n0 + rA1) * INF + kA1;
    unsigned short* lA0 = &lA[ch0 * 8];
    unsigned short* lA1 = &lA[ch1 * 8];
    unsigned short* lB0 = &lB[ch0 * 8];
    unsigned short* lB1 = &lB[ch1 * 8];

    const int frow = lane & 15;          // fragment row within 16x16 tile
    const int kgrp = (lane >> 4) * 8;    // k-group base (8 contiguous bf16)

    for (int k0 = 0; k0 < INF; k0 += BK) {
        __syncthreads();  // previous iter's LDS reads done before overwrite
        __builtin_amdgcn_global_load_lds((const __attribute__((address_space(1))) void*)(gA0 + k0),
                                         (__attribute__((address_space(3))) void*)lA0, 16, 0, 0);
        __builtin_amdgcn_global_load_lds((const __attribute__((address_space(1))) void*)(gA1 + k0),
                                         (__attribute__((address_space(3))) void*)lA1, 16, 0, 0);
        __builtin_amdgcn_global_load_lds((const __attribute__((address_space(1))) void*)(gB0 + k0),
                                         (__attribute__((address_space(3))) void*)lB0, 16, 0, 0);
        __builtin_amdgcn_global_load_lds((const __attribute__((address_space(1))) void*)(gB1 + k0),
                                         (__attribute__((address_space(3))) void*)lB1, 16, 0, 0);
        __syncthreads();  // compiler drains vmcnt(0) before s_barrier -> LDS data visible

        bf16x8 af[4], bfr[4];
#pragma unroll
        for (int i = 0; i < 4; i++)
            af[i] = *(const bf16x8*)&lA[(wm + i * 16 + frow) * BK + kgrp];
#pragma unroll
        for (int j = 0; j < 4; j++)
            bfr[j] = *(const bf16x8*)&lB[(wn + j * 16 + frow) * BK + kgrp];
#pragma unroll
        for (int i = 0; i < 4; i++)
#pragma unroll
            for (int j = 0; j < 4; j++)
                acc[i][j] = __builtin_amdgcn_mfma_f32_16x16x32_bf16(af[i], bfr[j], acc[i][j], 0, 0, 0);
    }

    // epilogue: C/D layout col=lane&15, row=(lane>>4)*4+reg  [m89/m91-verified]
    const int crow = (lane >> 4) * 4;
    const int ccol = lane & 15;
#pragma unroll
    for (int j = 0; j < 4; j++) {
        const int n = n0 + wn + j * 16 + ccol;
        const float bv = bias[n];
#pragma unroll
        for (int i = 0; i < 4; i++) {
            const int m = m0 + wm + i * 16 + crow;
#pragma unroll
            for (int r = 0; r < 4; r++)
                out[(size_t)(m + r) * OUTF + n] = acc[i][j][r] + bv;
        }
    }
}

// ---------------- fallback (ws too small): fused fp32 tiled GEMM ----------------
__global__ __launch_bounds__(256) void fused_fallback(const float* __restrict__ x,
                                                      const int* __restrict__ codes,
                                                      const float* __restrict__ absmax,
                                                      const float* __restrict__ codebook,
                                                      const float* __restrict__ bias,
                                                      float* __restrict__ out) {
    __shared__ float xs[64][17];
    __shared__ float wsm[64][17];
    __shared__ float cb[16];
    const int tid = threadIdx.x;
    if (tid < 16) cb[tid] = codebook[tid];
    const int m0 = blockIdx.y * 64, n0 = blockIdx.x * 64;
    float acc[4][4] = {};
    const int tr = tid >> 4, tc = tid & 15;
    for (int k0 = 0; k0 < INF; k0 += 16) {
        __syncthreads();
#pragma unroll
        for (int i = 0; i < 4; i++) {
            int e = i * 256 + tid;
            int r = e >> 4, c = e & 15;
            xs[r][c] = x[(size_t)(m0 + r) * INF + k0 + c];
            size_t widx = (size_t)(n0 + r) * INF + k0 + c;
            wsm[r][c] = cb[codes[widx]] * absmax[widx >> 6];
        }
        __syncthreads();
#pragma unroll
        for (int kk = 0; kk < 16; kk++) {
            float xv[4], wv[4];
#pragma unroll
            for (int i = 0; i < 4; i++) xv[i] = xs[tr * 4 + i][kk];
#pragma unroll
            for (int j = 0; j < 4; j++) wv[j] = wsm[tc * 4 + j][kk];
#pragma unroll
            for (int i = 0; i < 4; i++)
#pragma unroll
                for (int j = 0; j < 4; j++) acc[i][j] += xv[i] * wv[j];
        }
    }
#pragma unroll
    for (int i = 0; i < 4; i++)
#pragma unroll
        for (int j = 0; j < 4; j++) {
            int m = m0 + tr * 4 + i, n = n0 + tc * 4 + j;
            out[(size_t)m * OUTF + n] = acc[i][j] + bias[n];
        }
}

extern "C" void kernel_launch(void* const* d_in, const int* in_sizes, int n_in,
                              void* d_out, int out_size, void* d_ws, size_t ws_size,
                              hipStream_t stream) {
    const float* x        = (const float*)d_in[0];
    const int*   codes    = (const int*)d_in[1];
    const float* absmax   = (const float*)d_in[2];
    const float* codebook = (const float*)d_in[3];
    const float* bias     = (const float*)d_in[4];
    float* out = (float*)d_out;

    const size_t wbytes = (size_t)NCODES * 2;                 // 90.2 MB bf16 W
    const size_t xbytes = (size_t)TOKENS * INF * 2;           // 67.1 MB bf16 X

    if (ws_size >= wbytes + xbytes) {
        unsigned short* wq = (unsigned short*)d_ws;
        unsigned short* xq = (unsigned short*)((char*)d_ws + wbytes);
        dequant_w<<<NCODES / 2048, 256, 0, stream>>>(codes, absmax, codebook, wq);
        cast_x<<<(TOKENS * INF) / 2048, 256, 0, stream>>>(x, xq);
        gemm_bf16<<<dim3((OUTF / BN) * (TOKENS / BM)), 256, 0, stream>>>(xq, wq, bias, out);
    } else {
        dim3 grid(OUTF / 64, TOKENS / 64);
        fused_fallback<<<grid, 256, 0, stream>>>(x, codes, absmax, codebook, bias, out);
    }
}